// Round 2
// baseline (591.980 us; speedup 1.0000x reference)
//
#include <hip/hip_runtime.h>
#include <stdint.h>
#include <math.h>

typedef unsigned short ushort_t;                                 // bf16 bits
typedef short bf16x8 __attribute__((ext_vector_type(8)));        // 8 bf16 = 4 VGPRs
typedef float f32x4  __attribute__((ext_vector_type(4)));

#define B_   2
#define NQ_  1024
#define NK_  2048
#define D_   1024
#define H_   16
#define HD_  64

__device__ __forceinline__ ushort_t f2b(float f) {
  union { float f; unsigned int i; } x; x.f = f;
  unsigned int r = (x.i + 0x7FFFu + ((x.i >> 16) & 1u)) >> 16;   // RNE
  return (ushort_t)r;
}
// async global->LDS, 16B per lane, LDS dest = wave-uniform base + lane*16
__device__ __forceinline__ void g2l16(const void* g, void* l) {
  __builtin_amdgcn_global_load_lds(
      (const __attribute__((address_space(1))) unsigned int*)g,
      (__attribute__((address_space(3))) unsigned int*)l, 16, 0, 0);
}
__device__ __forceinline__ f32x4 mfma16(bf16x8 a, bf16x8 b, f32x4 c) {
  return __builtin_amdgcn_mfma_f32_16x16x32_bf16(a, b, c, 0, 0, 0);
}

// ---------------------------------------------------------------------------
// GEMM: C[M,N] = (A[M,K] @ Bt[N,K]^T + bias[N]) * alpha
// A: f32 (VGPR-convert staging) or bf16 (global_load_lds). C: bf16 or f32.
// 128x128 tile, BK=64, 256 threads = 4 waves (2x2), wave tile 64x64 (4x4 MFMA)
// ---------------------------------------------------------------------------
template <bool A_F32, bool C_F32>
__global__ __launch_bounds__(256) void gemm_bt(
    const void* __restrict__ Av, const ushort_t* __restrict__ Bt,
    const float* __restrict__ bias, void* __restrict__ Cv,
    int M, float alpha)
{
  constexpr int N = 1024, K = 1024, BK = 64;
  __shared__ __align__(16) ushort_t As[128 * BK];
  __shared__ __align__(16) ushort_t Bs[128 * BK];
  const int tid  = threadIdx.x;
  const int wid  = tid >> 6, lane = tid & 63;
  const int quad = lane >> 4, l15 = lane & 15;
  const int m0 = blockIdx.y * 128, n0 = blockIdx.x * 128;
  const int wm = (wid & 1) * 64,  wn = (wid >> 1) * 64;
  const int srow = tid >> 3, scol = (tid & 7) * 8;  // staging: 32 rows x 8-elem chunks

  const float*    Af = (const float*)Av;
  const ushort_t* Ab = (const ushort_t*)Av;
  const ushort_t* bBase = Bt + (size_t)(n0 + srow) * K + scol;
  ushort_t* asDst = As + tid * 8;
  ushort_t* bsDst = Bs + tid * 8;

  f32x4 acc[4][4];
#pragma unroll
  for (int i = 0; i < 4; i++)
#pragma unroll
    for (int j = 0; j < 4; j++) { f32x4 z = {0.f,0.f,0.f,0.f}; acc[i][j] = z; }

  for (int k0 = 0; k0 < K; k0 += BK) {
    __syncthreads();
#pragma unroll
    for (int j = 0; j < 4; j++)
      g2l16(bBase + (size_t)j * 32 * K + k0, bsDst + j * 2048);
    if constexpr (A_F32) {
#pragma unroll
      for (int j = 0; j < 4; j++) {
        const float* p = Af + (size_t)(m0 + srow + j * 32) * K + k0 + scol;
        float4 x = *(const float4*)p;
        float4 y = *(const float4*)(p + 4);
        bf16x8 v;
        ((ushort_t*)&v)[0] = f2b(x.x); ((ushort_t*)&v)[1] = f2b(x.y);
        ((ushort_t*)&v)[2] = f2b(x.z); ((ushort_t*)&v)[3] = f2b(x.w);
        ((ushort_t*)&v)[4] = f2b(y.x); ((ushort_t*)&v)[5] = f2b(y.y);
        ((ushort_t*)&v)[6] = f2b(y.z); ((ushort_t*)&v)[7] = f2b(y.w);
        *(bf16x8*)(asDst + j * 2048) = v;
      }
    } else {
#pragma unroll
      for (int j = 0; j < 4; j++)
        g2l16(Ab + (size_t)(m0 + srow + j * 32) * K + k0 + scol, asDst + j * 2048);
    }
    asm volatile("s_waitcnt vmcnt(0)" ::: "memory");
    __syncthreads();
#pragma unroll
    for (int ks = 0; ks < 2; ks++) {
      bf16x8 af[4], bfr[4];
#pragma unroll
      for (int t = 0; t < 4; t++) {
        af[t]  = *(const bf16x8*)(As + (wm + t * 16 + l15) * BK + ks * 32 + quad * 8);
        bfr[t] = *(const bf16x8*)(Bs + (wn + t * 16 + l15) * BK + ks * 32 + quad * 8);
      }
#pragma unroll
      for (int mt = 0; mt < 4; mt++)
#pragma unroll
        for (int nt = 0; nt < 4; nt++)
          acc[mt][nt] = mfma16(af[mt], bfr[nt], acc[mt][nt]);
    }
  }
  // epilogue: C/D layout col=lane&15, row=quad*4+reg
  float bn[4];
#pragma unroll
  for (int nt = 0; nt < 4; nt++) bn[nt] = bias[n0 + wn + nt * 16 + l15];
#pragma unroll
  for (int mt = 0; mt < 4; mt++) {
    const int mb = m0 + wm + mt * 16 + quad * 4;
#pragma unroll
    for (int nt = 0; nt < 4; nt++) {
      const int n = n0 + wn + nt * 16 + l15;
#pragma unroll
      for (int r = 0; r < 4; r++) {
        const float val = (acc[mt][nt][r] + bn[nt]) * alpha;
        if constexpr (C_F32) ((float*)Cv)[(size_t)(mb + r) * N + n] = val;
        else ((ushort_t*)Cv)[(size_t)(mb + r) * N + n] = f2b(val);
      }
    }
  }
}

// ---------------------------------------------------------------------------
// weight transpose + convert: WT[n][k] = bf16(W[k][n]), 1024x1024, f32 in
// ---------------------------------------------------------------------------
struct WTP { const float* src[4]; ushort_t* dst[4]; };

__global__ __launch_bounds__(256) void wtrans_k(WTP p) {
  constexpr int Kd = 1024, Nd = 1024;
  __shared__ ushort_t t[64][72];
  const float* X = p.src[blockIdx.z];
  ushort_t*    Y = p.dst[blockIdx.z];
  const int rt = blockIdx.y * 64, ct = blockIdx.x * 64;
  const int tid = threadIdx.x;
  const int lr = tid >> 3, lc = (tid & 7) * 8;
#pragma unroll
  for (int j = 0; j < 2; j++) {
    const float* px = X + (size_t)(rt + j * 32 + lr) * Nd + ct + lc;
    float4 x = *(const float4*)px;
    float4 y = *(const float4*)(px + 4);
    ushort_t* tr = &t[j * 32 + lr][lc];
    tr[0] = f2b(x.x); tr[1] = f2b(x.y); tr[2] = f2b(x.z); tr[3] = f2b(x.w);
    tr[4] = f2b(y.x); tr[5] = f2b(y.y); tr[6] = f2b(y.z); tr[7] = f2b(y.w);
  }
  __syncthreads();
#pragma unroll
  for (int j = 0; j < 2; j++) {
    bf16x8 w;
#pragma unroll
    for (int i = 0; i < 8; i++) ((ushort_t*)&w)[i] = t[lc + i][j * 32 + lr];
    *(bf16x8*)(Y + (size_t)(ct + j * 32 + lr) * Kd + rt + lc) = w;
  }
}

// ---------------------------------------------------------------------------
// bf16 64x64-tile transpose (Vp [NK][D] -> Vt [D][NK]), batched over z
// ---------------------------------------------------------------------------
struct TPtrs { const ushort_t* src[2]; ushort_t* dst[2]; };

__global__ __launch_bounds__(256) void vtrans_k(TPtrs p, int R, int C) {
  __shared__ ushort_t t[64][68];
  const ushort_t* X = p.src[blockIdx.z];
  ushort_t*       Y = p.dst[blockIdx.z];
  const int rt = blockIdx.y * 64, ct = blockIdx.x * 64;
  const int tid = threadIdx.x;
  const int lr = tid >> 3, lc = (tid & 7) * 8;
#pragma unroll
  for (int j = 0; j < 2; j++) {
    bf16x8 v = *(const bf16x8*)(X + (size_t)(rt + j * 32 + lr) * C + ct + lc);
#pragma unroll
    for (int i = 0; i < 8; i++) t[j * 32 + lr][lc + i] = ((ushort_t*)&v)[i];
  }
  __syncthreads();
#pragma unroll
  for (int j = 0; j < 2; j++) {
    bf16x8 w;
#pragma unroll
    for (int i = 0; i < 8; i++) ((ushort_t*)&w)[i] = t[lc + i][j * 32 + lr];
    *(bf16x8*)(Y + (size_t)(ct + j * 32 + lr) * R + rt + lc) = w;
  }
}

// ---------------------------------------------------------------------------
// mask prep: sniff uint8 vs int32 encoding, emit f32 additive mask (0 / -1e30)
// ---------------------------------------------------------------------------
__global__ __launch_bounds__(256) void mask_prep(const unsigned char* __restrict__ mraw,
                                                 float* __restrict__ maskf, int n) {
  __shared__ int is_u8;
  const int tid = threadIdx.x;
  if (tid == 0) is_u8 = 0;
  __syncthreads();
  int nz = 0;
  for (int i = tid; i < n; i += 256)
    if ((i & 3) != 0 && mraw[i] != 0) nz = 1;
  if (nz) is_u8 = 1;            // benign race, idempotent
  __syncthreads();
  const int u8 = is_u8;
  const int* mi = (const int*)mraw;
  for (int k = tid; k < n; k += 256) {
    int v = u8 ? (int)mraw[k] : mi[k];   // reads beyond n bytes only if truly int32
    maskf[k] = v ? -1e30f : 0.0f;
  }
}

// ---------------------------------------------------------------------------
// flash attention: grid (NQ/64, H, B), 256 threads = 4 waves x 16 q-rows
// Qp pre-scaled by SCALE. Kp [B,NK,D] bf16, Vt [B,D,NK] bf16, bias f32.
// ---------------------------------------------------------------------------
__global__ __launch_bounds__(256) void flash_attn(
    const ushort_t* __restrict__ Qp, const ushort_t* __restrict__ Kp,
    const ushort_t* __restrict__ Vt, const float* __restrict__ bias,
    const float* __restrict__ maskf, ushort_t* __restrict__ Ao)
{
  __shared__ __align__(16) ushort_t Ks[64 * 64];     // [key][hd]
  __shared__ __align__(16) ushort_t Vs[64 * 64];     // [hd][key]
  __shared__ __align__(16) ushort_t Ps[4][16 * 64];  // per-wave P staging [q][key]
  const int b = blockIdx.z, h = blockIdx.y, q0 = blockIdx.x * 64;
  const int tid  = threadIdx.x, wid = tid >> 6, lane = tid & 63;
  const int quad = lane >> 4, l15 = lane & 15;
  const int qw   = q0 + wid * 16;
  const int srow = tid >> 3, scol = (tid & 7) * 8;

  // Q A-fragments: m = l15 (q-row), k = quad*8+j (hd)
  bf16x8 qf[2];
#pragma unroll
  for (int ks = 0; ks < 2; ks++)
    qf[ks] = *(const bf16x8*)(Qp + (size_t)(b * NQ_ + qw + l15) * D_ + h * HD_ + ks * 32 + quad * 8);

  f32x4 o[4];
#pragma unroll
  for (int nt = 0; nt < 4; nt++) { f32x4 z = {0.f,0.f,0.f,0.f}; o[nt] = z; }
  float mrow[4] = {-INFINITY, -INFINITY, -INFINITY, -INFINITY};
  float lrow[4] = {0.f, 0.f, 0.f, 0.f};

  const float*    biasBase = bias + ((size_t)(b * H_ + h) * NQ_ + qw) * NK_;
  const float*    mBase    = maskf + b * NK_;
  const ushort_t* kBase    = Kp + (size_t)(b * NK_ + srow) * D_ + h * HD_ + scol;
  const ushort_t* vBase    = Vt + (size_t)(b * D_ + h * HD_ + srow) * NK_ + scol;

  for (int k0 = 0; k0 < NK_; k0 += 64) {
    __syncthreads();
#pragma unroll
    for (int j = 0; j < 2; j++) {
      g2l16(kBase + (size_t)(k0 + j * 32) * D_, Ks + tid * 8 + j * 2048);
      g2l16(vBase + (size_t)j * 32 * NK_ + k0, Vs + tid * 8 + j * 2048);
    }
    asm volatile("s_waitcnt vmcnt(0)" ::: "memory");
    __syncthreads();

    // S = Q K^T (Qp pre-scaled)
    f32x4 s[4];
#pragma unroll
    for (int nt = 0; nt < 4; nt++) { f32x4 z = {0.f,0.f,0.f,0.f}; s[nt] = z; }
#pragma unroll
    for (int ks = 0; ks < 2; ks++)
#pragma unroll
      for (int nt = 0; nt < 4; nt++) {
        bf16x8 kf = *(const bf16x8*)(Ks + (nt * 16 + l15) * 64 + ks * 32 + quad * 8);
        s[nt] = mfma16(qf[ks], kf, s[nt]);
      }

    // logits: z = s + bias + mask   (row = quad*4+r, key = k0 + nt*16 + l15)
    float z[4][4];
#pragma unroll
    for (int nt = 0; nt < 4; nt++) {
      const float mk = mBase[k0 + nt * 16 + l15];
#pragma unroll
      for (int r = 0; r < 4; r++)
        z[nt][r] = s[nt][r] + biasBase[(size_t)(quad * 4 + r) * NK_ + k0 + nt * 16 + l15] + mk;
    }

    // online softmax: row max over 4 tiles + 16 lanes of quad
    float alpha_[4];
#pragma unroll
    for (int r = 0; r < 4; r++) {
      float v = fmaxf(fmaxf(z[0][r], z[1][r]), fmaxf(z[2][r], z[3][r]));
      v = fmaxf(v, __shfl_xor(v, 1)); v = fmaxf(v, __shfl_xor(v, 2));
      v = fmaxf(v, __shfl_xor(v, 4)); v = fmaxf(v, __shfl_xor(v, 8));
      float mn = fmaxf(mrow[r], v);
      alpha_[r] = __expf(mrow[r] - mn);
      mrow[r] = mn;
    }
    float rsum[4] = {0.f, 0.f, 0.f, 0.f};
#pragma unroll
    for (int nt = 0; nt < 4; nt++)
#pragma unroll
      for (int r = 0; r < 4; r++) {
        float p = __expf(z[nt][r] - mrow[r]);
        rsum[r] += p;
        Ps[wid][(quad * 4 + r) * 64 + nt * 16 + l15] = f2b(p);
      }
#pragma unroll
    for (int r = 0; r < 4; r++) {
      float v = rsum[r];
      v += __shfl_xor(v, 1); v += __shfl_xor(v, 2);
      v += __shfl_xor(v, 4); v += __shfl_xor(v, 8);
      lrow[r] = lrow[r] * alpha_[r] + v;
    }
#pragma unroll
    for (int nt = 0; nt < 4; nt++) {
      f32x4 t = o[nt];
#pragma unroll
      for (int r = 0; r < 4; r++) t[r] *= alpha_[r];
      o[nt] = t;
    }
    // O += P @ V   (P A-frag via per-wave LDS round-trip; in-order LDS pipe,
    // same-wave write->read needs no barrier)
#pragma unroll
    for (int ks = 0; ks < 2; ks++) {
      bf16x8 pa = *(const bf16x8*)(&Ps[wid][l15 * 64 + ks * 32 + quad * 8]);
#pragma unroll
      for (int nt = 0; nt < 4; nt++) {
        bf16x8 vf = *(const bf16x8*)(Vs + (nt * 16 + l15) * 64 + ks * 32 + quad * 8);
        o[nt] = mfma16(pa, vf, o[nt]);
      }
    }
  }
  // normalize + store [B,NQ,D] (bf16 intermediate)
#pragma unroll
  for (int nt = 0; nt < 4; nt++)
#pragma unroll
    for (int r = 0; r < 4; r++)
      Ao[(size_t)(b * NQ_ + qw + quad * 4 + r) * D_ + h * HD_ + nt * 16 + l15]
          = f2b(o[nt][r] / lrow[r]);
}

// ---------------------------------------------------------------------------
extern "C" void kernel_launch(void* const* d_in, const int* in_sizes, int n_in,
                              void* d_out, int out_size, void* d_ws, size_t ws_size,
                              hipStream_t stream)
{
  const float* query = (const float*)d_in[0];
  const float* key   = (const float*)d_in[1];
  const float* value = (const float*)d_in[2];
  const float* abias = (const float*)d_in[3];
  const unsigned char* mask = (const unsigned char*)d_in[4];
  const float* Wq = (const float*)d_in[5];
  const float* bq = (const float*)d_in[6];
  const float* Wk = (const float*)d_in[7];
  const float* bk = (const float*)d_in[8];
  const float* Wv = (const float*)d_in[9];
  const float* bv = (const float*)d_in[10];
  const float* Wo = (const float*)d_in[11];
  const float* bo = (const float*)d_in[12];
  float* out = (float*)d_out;

  char* ws = (char*)d_ws;
  const size_t MB = 1ull << 20;
  ushort_t* WqT   = (ushort_t*)(ws + 0 * MB);   // 2 MB
  ushort_t* WkT   = (ushort_t*)(ws + 2 * MB);   // 2 MB
  ushort_t* WvT   = (ushort_t*)(ws + 4 * MB);   // 2 MB
  ushort_t* WoT   = (ushort_t*)(ws + 6 * MB);   // 2 MB
  float*    maskf = (float*)   (ws + 8 * MB);   // 16 KB
  ushort_t* Qp    = (ushort_t*)(ws + 9 * MB);   // 4 MB
  ushort_t* Kp    = (ushort_t*)(ws + 13 * MB);  // 8 MB
  ushort_t* Vp    = (ushort_t*)(ws + 21 * MB);  // 8 MB
  ushort_t* Vt    = (ushort_t*)(ws + 29 * MB);  // 8 MB
  ushort_t* Ao    = (ushort_t*)(ws + 37 * MB);  // 4 MB  (total 41 MB)

  // 1) weights: f32 [K][N] -> bf16 [N][K]
  WTP wt; wt.src[0] = Wq; wt.src[1] = Wk; wt.src[2] = Wv; wt.src[3] = Wo;
  wt.dst[0] = WqT; wt.dst[1] = WkT; wt.dst[2] = WvT; wt.dst[3] = WoT;
  wtrans_k<<<dim3(16, 16, 4), 256, 0, stream>>>(wt);

  // 2) mask -> additive f32
  mask_prep<<<1, 256, 0, stream>>>(mask, maskf, B_ * NK_);

  // 3) projections (SCALE folded into Qp), f32 A -> bf16 C
  gemm_bt<true, false><<<dim3(8, 16), 256, 0, stream>>>(query, WqT, bq, Qp, B_ * NQ_, 0.125f);
  gemm_bt<true, false><<<dim3(8, 32), 256, 0, stream>>>(key,   WkT, bk, Kp, B_ * NK_, 1.0f);
  gemm_bt<true, false><<<dim3(8, 32), 256, 0, stream>>>(value, WvT, bv, Vp, B_ * NK_, 1.0f);

  // 4) V -> Vt [B, D, NK]
  TPtrs vt; vt.src[0] = Vp; vt.src[1] = Vp + (size_t)NK_ * D_;
  vt.dst[0] = Vt; vt.dst[1] = Vt + (size_t)D_ * NK_;
  vtrans_k<<<dim3(16, 32, 2), 256, 0, stream>>>(vt, NK_, D_);

  // 5) fused attention
  flash_attn<<<dim3(NQ_ / 64, H_, B_), 256, 0, stream>>>(Qp, Kp, Vt, abias, maskf, Ao);

  // 6) output projection -> d_out (f32)
  gemm_bt<false, true><<<dim3(8, 16), 256, 0, stream>>>(Ao, WoT, bo, out, B_ * NQ_, 1.0f);
}

// Round 3
// 569.530 us; speedup vs baseline: 1.0394x; 1.0394x over previous
//
#include <hip/hip_runtime.h>
#include <stdint.h>
#include <math.h>

typedef unsigned short ushort_t;                                 // bf16 bits
typedef short bf16x8 __attribute__((ext_vector_type(8)));        // 8 bf16 = 4 VGPRs
typedef float f32x4  __attribute__((ext_vector_type(4)));

#define B_   2
#define NQ_  1024
#define NK_  2048
#define D_   1024
#define H_   16
#define HD_  64

__device__ __forceinline__ ushort_t f2b(float f) {               // RNE (cold paths)
  union { float f; unsigned int i; } x; x.f = f;
  unsigned int r = (x.i + 0x7FFFu + ((x.i >> 16) & 1u)) >> 16;
  return (ushort_t)r;
}
__device__ __forceinline__ ushort_t f2b_fast(float f) {          // round-to-nearest-away
  union { float f; unsigned int i; } x; x.f = f;
  return (ushort_t)((x.i + 0x8000u) >> 16);
}
// async global->LDS, 16B per lane, LDS dest = wave-uniform base + lane*16
__device__ __forceinline__ void g2l16(const void* g, void* l) {
  __builtin_amdgcn_global_load_lds(
      (const __attribute__((address_space(1))) unsigned int*)g,
      (__attribute__((address_space(3))) unsigned int*)l, 16, 0, 0);
}
__device__ __forceinline__ f32x4 mfma16(bf16x8 a, bf16x8 b, f32x4 c) {
  return __builtin_amdgcn_mfma_f32_16x16x32_bf16(a, b, c, 0, 0, 0);
}

// ---------------------------------------------------------------------------
// GEMM tile body: C[128,128] = (A[128,K] @ Bt[128,K]^T + bias) * alpha
// A: f32 (VGPR cheap-pack staging) or bf16 (global_load_lds). C: bf16 or f32.
// BK=64, 256 threads = 4 waves (2x2), wave tile 64x64 (4x4 MFMA)
// ---------------------------------------------------------------------------
template <bool A_F32, bool C_F32>
__device__ __forceinline__ void gemm_tile(
    const void* __restrict__ Av, const ushort_t* __restrict__ Bt,
    const float* __restrict__ bias, void* __restrict__ Cv,
    int m0, int n0, float alpha)
{
  constexpr int N = 1024, K = 1024, BK = 64;
  __shared__ __align__(16) ushort_t As[128 * BK];
  __shared__ __align__(16) ushort_t Bs[128 * BK];
  const int tid  = threadIdx.x;
  const int wid  = tid >> 6, lane = tid & 63;
  const int quad = lane >> 4, l15 = lane & 15;
  const int wm = (wid & 1) * 64,  wn = (wid >> 1) * 64;
  const int srow = tid >> 3, scol = (tid & 7) * 8;  // staging: 32 rows x 8-elem chunks

  const float*    Af = (const float*)Av;
  const ushort_t* Ab = (const ushort_t*)Av;
  const ushort_t* bBase = Bt + (size_t)(n0 + srow) * K + scol;
  ushort_t* asDst = As + tid * 8;
  ushort_t* bsDst = Bs + tid * 8;

  f32x4 acc[4][4];
#pragma unroll
  for (int i = 0; i < 4; i++)
#pragma unroll
    for (int j = 0; j < 4; j++) { f32x4 z = {0.f,0.f,0.f,0.f}; acc[i][j] = z; }

  for (int k0 = 0; k0 < K; k0 += BK) {
    __syncthreads();
#pragma unroll
    for (int j = 0; j < 4; j++)
      g2l16(bBase + (size_t)j * 32 * K + k0, bsDst + j * 2048);
    if constexpr (A_F32) {
#pragma unroll
      for (int j = 0; j < 4; j++) {
        const unsigned* p = (const unsigned*)(Af + (size_t)(m0 + srow + j * 32) * K + k0 + scol);
        uint4 x = *(const uint4*)p;
        uint4 y = *(const uint4*)(p + 4);
        uint4 o;
        o.x = ((x.y + 0x8000u) & 0xFFFF0000u) | ((x.x + 0x8000u) >> 16);
        o.y = ((x.w + 0x8000u) & 0xFFFF0000u) | ((x.z + 0x8000u) >> 16);
        o.z = ((y.y + 0x8000u) & 0xFFFF0000u) | ((y.x + 0x8000u) >> 16);
        o.w = ((y.w + 0x8000u) & 0xFFFF0000u) | ((y.z + 0x8000u) >> 16);
        *(uint4*)(asDst + j * 2048) = o;
      }
    } else {
#pragma unroll
      for (int j = 0; j < 4; j++)
        g2l16(Ab + (size_t)(m0 + srow + j * 32) * K + k0 + scol, asDst + j * 2048);
    }
    asm volatile("s_waitcnt vmcnt(0)" ::: "memory");
    __syncthreads();
#pragma unroll
    for (int ks = 0; ks < 2; ks++) {
      bf16x8 af[4], bfr[4];
#pragma unroll
      for (int t = 0; t < 4; t++) {
        af[t]  = *(const bf16x8*)(As + (wm + t * 16 + l15) * BK + ks * 32 + quad * 8);
        bfr[t] = *(const bf16x8*)(Bs + (wn + t * 16 + l15) * BK + ks * 32 + quad * 8);
      }
#pragma unroll
      for (int mt = 0; mt < 4; mt++)
#pragma unroll
        for (int nt = 0; nt < 4; nt++)
          acc[mt][nt] = mfma16(af[mt], bfr[nt], acc[mt][nt]);
    }
  }
  // epilogue: C/D layout col=lane&15, row=quad*4+reg
  float bn[4];
#pragma unroll
  for (int nt = 0; nt < 4; nt++) bn[nt] = bias[n0 + wn + nt * 16 + l15];
#pragma unroll
  for (int mt = 0; mt < 4; mt++) {
    const int mb = m0 + wm + mt * 16 + quad * 4;
#pragma unroll
    for (int nt = 0; nt < 4; nt++) {
      const int n = n0 + wn + nt * 16 + l15;
#pragma unroll
      for (int r = 0; r < 4; r++) {
        const float val = (acc[mt][nt][r] + bn[nt]) * alpha;
        if constexpr (C_F32) ((float*)Cv)[(size_t)(mb + r) * N + n] = val;
        else ((ushort_t*)Cv)[(size_t)(mb + r) * N + n] = f2b_fast(val);
      }
    }
  }
}

// fused Q/K/V projections: grid (8, 80); y<16 -> Q, y<48 -> K, else V
struct Proj3P {
  const float* A[3]; const ushort_t* Bt[3]; const float* bias[3];
  ushort_t* C[3]; float alpha[3];
};

__global__ __launch_bounds__(256) void proj3_k(Proj3P p) {
  const int y = blockIdx.y;
  const int i = (y < 16) ? 0 : (y < 48 ? 1 : 2);
  const int my = y - ((i == 0) ? 0 : (i == 1) ? 16 : 48);
  gemm_tile<true, false>(p.A[i], p.Bt[i], p.bias[i], p.C[i],
                         my * 128, blockIdx.x * 128, p.alpha[i]);
}

__global__ __launch_bounds__(256) void gemm_out_k(
    const ushort_t* __restrict__ A, const ushort_t* __restrict__ Bt,
    const float* __restrict__ bias, float* __restrict__ C) {
  gemm_tile<false, true>(A, Bt, bias, C, blockIdx.y * 128, blockIdx.x * 128, 1.0f);
}

// ---------------------------------------------------------------------------
// weight transpose + convert: WT[n][k] = bf16(W[k][n]), 1024x1024, f32 in
// ---------------------------------------------------------------------------
struct WTP { const float* src[4]; ushort_t* dst[4]; };

__global__ __launch_bounds__(256) void wtrans_k(WTP p) {
  constexpr int Kd = 1024, Nd = 1024;
  __shared__ ushort_t t[64][72];
  const float* X = p.src[blockIdx.z];
  ushort_t*    Y = p.dst[blockIdx.z];
  const int rt = blockIdx.y * 64, ct = blockIdx.x * 64;
  const int tid = threadIdx.x;
  const int lr = tid >> 3, lc = (tid & 7) * 8;
#pragma unroll
  for (int j = 0; j < 2; j++) {
    const float* px = X + (size_t)(rt + j * 32 + lr) * Nd + ct + lc;
    float4 x = *(const float4*)px;
    float4 y = *(const float4*)(px + 4);
    ushort_t* tr = &t[j * 32 + lr][lc];
    tr[0] = f2b(x.x); tr[1] = f2b(x.y); tr[2] = f2b(x.z); tr[3] = f2b(x.w);
    tr[4] = f2b(y.x); tr[5] = f2b(y.y); tr[6] = f2b(y.z); tr[7] = f2b(y.w);
  }
  __syncthreads();
#pragma unroll
  for (int j = 0; j < 2; j++) {
    bf16x8 w;
#pragma unroll
    for (int i = 0; i < 8; i++) ((ushort_t*)&w)[i] = t[lc + i][j * 32 + lr];
    *(bf16x8*)(Y + (size_t)(ct + j * 32 + lr) * Kd + rt + lc) = w;
  }
}

// ---------------------------------------------------------------------------
// bf16 64x64-tile transpose (Vp [NK][D] -> Vt [D][NK]), batched over z
// ---------------------------------------------------------------------------
struct TPtrs { const ushort_t* src[2]; ushort_t* dst[2]; };

__global__ __launch_bounds__(256) void vtrans_k(TPtrs p, int R, int C) {
  __shared__ ushort_t t[64][68];
  const ushort_t* X = p.src[blockIdx.z];
  ushort_t*       Y = p.dst[blockIdx.z];
  const int rt = blockIdx.y * 64, ct = blockIdx.x * 64;
  const int tid = threadIdx.x;
  const int lr = tid >> 3, lc = (tid & 7) * 8;
#pragma unroll
  for (int j = 0; j < 2; j++) {
    bf16x8 v = *(const bf16x8*)(X + (size_t)(rt + j * 32 + lr) * C + ct + lc);
#pragma unroll
    for (int i = 0; i < 8; i++) t[j * 32 + lr][lc + i] = ((ushort_t*)&v)[i];
  }
  __syncthreads();
#pragma unroll
  for (int j = 0; j < 2; j++) {
    bf16x8 w;
#pragma unroll
    for (int i = 0; i < 8; i++) ((ushort_t*)&w)[i] = t[lc + i][j * 32 + lr];
    *(bf16x8*)(Y + (size_t)(ct + j * 32 + lr) * R + rt + lc) = w;
  }
}

// ---------------------------------------------------------------------------
// mask prep: sniff uint8 vs int32 encoding, emit f32 additive mask (0 / -1e30)
// ---------------------------------------------------------------------------
__global__ __launch_bounds__(256) void mask_prep(const unsigned char* __restrict__ mraw,
                                                 float* __restrict__ maskf, int n) {
  __shared__ int is_u8;
  const int tid = threadIdx.x;
  if (tid == 0) is_u8 = 0;
  __syncthreads();
  int nz = 0;
  for (int i = tid; i < n; i += 256)
    if ((i & 3) != 0 && mraw[i] != 0) nz = 1;
  if (nz) is_u8 = 1;            // benign race, idempotent
  __syncthreads();
  const int u8 = is_u8;
  const int* mi = (const int*)mraw;
  for (int k = tid; k < n; k += 256) {
    int v = u8 ? (int)mraw[k] : mi[k];   // reads beyond n bytes only if truly int32
    maskf[k] = v ? -1e30f : 0.0f;
  }
}

// ---------------------------------------------------------------------------
// flash attention: grid (NQ/64, H, B), 256 threads = 4 waves x 16 q-rows
// Qp pre-scaled by SCALE. Kp [B,NK,D] bf16, Vt [B,D,NK] bf16, bias f32
// staged per-tile into LDS via global_load_lds (coalesced 256B runs).
// ---------------------------------------------------------------------------
__global__ __launch_bounds__(256) void flash_attn(
    const ushort_t* __restrict__ Qp, const ushort_t* __restrict__ Kp,
    const ushort_t* __restrict__ Vt, const float* __restrict__ bias,
    const float* __restrict__ maskf, ushort_t* __restrict__ Ao)
{
  __shared__ __align__(16) ushort_t Ks[64 * 64];     // [key][hd]      8 KB
  __shared__ __align__(16) ushort_t Vs[64 * 64];     // [hd][key]      8 KB
  __shared__ __align__(16) ushort_t Ps[4][16 * 64];  // per-wave P     8 KB
  __shared__ __align__(16) float    Bf[64 * 64];     // bias tile     16 KB
  const int b = blockIdx.z, h = blockIdx.y, q0 = blockIdx.x * 64;
  const int tid  = threadIdx.x, wid = tid >> 6, lane = tid & 63;
  const int quad = lane >> 4, l15 = lane & 15;
  const int qw   = q0 + wid * 16;
  const int srow = tid >> 3, scol = (tid & 7) * 8;

  // Q A-fragments: m = l15 (q-row), k = quad*8+j (hd)
  bf16x8 qf[2];
#pragma unroll
  for (int ks = 0; ks < 2; ks++)
    qf[ks] = *(const bf16x8*)(Qp + (size_t)(b * NQ_ + qw + l15) * D_ + h * HD_ + ks * 32 + quad * 8);

  f32x4 o[4];
#pragma unroll
  for (int nt = 0; nt < 4; nt++) { f32x4 z = {0.f,0.f,0.f,0.f}; o[nt] = z; }
  float mrow[4] = {-INFINITY, -INFINITY, -INFINITY, -INFINITY};
  float lrow[4] = {0.f, 0.f, 0.f, 0.f};

  const float*    biasBase = bias + ((size_t)(b * H_ + h) * NQ_ + q0) * NK_;
  const float*    mBase    = maskf + b * NK_;
  const ushort_t* kBase    = Kp + (size_t)(b * NK_ + srow) * D_ + h * HD_ + scol;
  const ushort_t* vBase    = Vt + (size_t)(b * D_ + h * HD_ + srow) * NK_ + scol;
  // per-wave bias staging addresses: 4 issues x 4 rows, 16 lanes x 16B per row
  const int bRow0 = wid * 16 + (lane >> 4);
  const int bCol  = (l15) * 4;

  for (int k0 = 0; k0 < NK_; k0 += 64) {
    __syncthreads();
#pragma unroll
    for (int j = 0; j < 2; j++) {
      g2l16(kBase + (size_t)(k0 + j * 32) * D_, Ks + tid * 8 + j * 2048);
      g2l16(vBase + (size_t)j * 32 * NK_ + k0, Vs + tid * 8 + j * 2048);
    }
#pragma unroll
    for (int j = 0; j < 4; j++)
      g2l16(biasBase + (size_t)(bRow0 + j * 4) * NK_ + k0 + bCol,
            (char*)Bf + (wid * 16 + j * 4) * 256);
    asm volatile("s_waitcnt vmcnt(0)" ::: "memory");
    __syncthreads();

    // S = Q K^T (Qp pre-scaled)
    f32x4 s[4];
#pragma unroll
    for (int nt = 0; nt < 4; nt++) { f32x4 z = {0.f,0.f,0.f,0.f}; s[nt] = z; }
#pragma unroll
    for (int ks = 0; ks < 2; ks++)
#pragma unroll
      for (int nt = 0; nt < 4; nt++) {
        bf16x8 kf = *(const bf16x8*)(Ks + (nt * 16 + l15) * 64 + ks * 32 + quad * 8);
        s[nt] = mfma16(qf[ks], kf, s[nt]);
      }

    // logits: z = s + bias + mask   (row = quad*4+r, key = k0 + nt*16 + l15)
    float z[4][4];
#pragma unroll
    for (int nt = 0; nt < 4; nt++) {
      const float mk = mBase[k0 + nt * 16 + l15];
#pragma unroll
      for (int r = 0; r < 4; r++)
        z[nt][r] = s[nt][r] + Bf[(wid * 16 + quad * 4 + r) * 64 + nt * 16 + l15] + mk;
    }

    // online softmax: row max over 4 tiles + 16 lanes of quad
    float alpha_[4];
#pragma unroll
    for (int r = 0; r < 4; r++) {
      float v = fmaxf(fmaxf(z[0][r], z[1][r]), fmaxf(z[2][r], z[3][r]));
      v = fmaxf(v, __shfl_xor(v, 1)); v = fmaxf(v, __shfl_xor(v, 2));
      v = fmaxf(v, __shfl_xor(v, 4)); v = fmaxf(v, __shfl_xor(v, 8));
      float mn = fmaxf(mrow[r], v);
      alpha_[r] = __expf(mrow[r] - mn);
      mrow[r] = mn;
    }
    float rsum[4] = {0.f, 0.f, 0.f, 0.f};
#pragma unroll
    for (int nt = 0; nt < 4; nt++)
#pragma unroll
      for (int r = 0; r < 4; r++) {
        float p = __expf(z[nt][r] - mrow[r]);
        rsum[r] += p;
        Ps[wid][(quad * 4 + r) * 64 + nt * 16 + l15] = f2b_fast(p);
      }
#pragma unroll
    for (int r = 0; r < 4; r++) {
      float v = rsum[r];
      v += __shfl_xor(v, 1); v += __shfl_xor(v, 2);
      v += __shfl_xor(v, 4); v += __shfl_xor(v, 8);
      lrow[r] = lrow[r] * alpha_[r] + v;
    }
#pragma unroll
    for (int nt = 0; nt < 4; nt++) {
      f32x4 t = o[nt];
#pragma unroll
      for (int r = 0; r < 4; r++) t[r] *= alpha_[r];
      o[nt] = t;
    }
    // O += P @ V   (P A-frag via per-wave LDS round-trip; in-order LDS pipe,
    // same-wave write->read needs no barrier)
#pragma unroll
    for (int ks = 0; ks < 2; ks++) {
      bf16x8 pa = *(const bf16x8*)(&Ps[wid][l15 * 64 + ks * 32 + quad * 8]);
#pragma unroll
      for (int nt = 0; nt < 4; nt++) {
        bf16x8 vf = *(const bf16x8*)(Vs + (nt * 16 + l15) * 64 + ks * 32 + quad * 8);
        o[nt] = mfma16(pa, vf, o[nt]);
      }
    }
  }
  // normalize + store [B,NQ,D] (bf16 intermediate)
#pragma unroll
  for (int nt = 0; nt < 4; nt++)
#pragma unroll
    for (int r = 0; r < 4; r++)
      Ao[(size_t)(b * NQ_ + qw + quad * 4 + r) * D_ + h * HD_ + nt * 16 + l15]
          = f2b_fast(o[nt][r] / lrow[r]);
}

// ---------------------------------------------------------------------------
extern "C" void kernel_launch(void* const* d_in, const int* in_sizes, int n_in,
                              void* d_out, int out_size, void* d_ws, size_t ws_size,
                              hipStream_t stream)
{
  const float* query = (const float*)d_in[0];
  const float* key   = (const float*)d_in[1];
  const float* value = (const float*)d_in[2];
  const float* abias = (const float*)d_in[3];
  const unsigned char* mask = (const unsigned char*)d_in[4];
  const float* Wq = (const float*)d_in[5];
  const float* bq = (const float*)d_in[6];
  const float* Wk = (const float*)d_in[7];
  const float* bk = (const float*)d_in[8];
  const float* Wv = (const float*)d_in[9];
  const float* bv = (const float*)d_in[10];
  const float* Wo = (const float*)d_in[11];
  const float* bo = (const float*)d_in[12];
  float* out = (float*)d_out;

  char* ws = (char*)d_ws;
  const size_t MB = 1ull << 20;
  ushort_t* WqT   = (ushort_t*)(ws + 0 * MB);   // 2 MB
  ushort_t* WkT   = (ushort_t*)(ws + 2 * MB);   // 2 MB
  ushort_t* WvT   = (ushort_t*)(ws + 4 * MB);   // 2 MB
  ushort_t* WoT   = (ushort_t*)(ws + 6 * MB);   // 2 MB
  float*    maskf = (float*)   (ws + 8 * MB);   // 16 KB
  ushort_t* Qp    = (ushort_t*)(ws + 9 * MB);   // 4 MB
  ushort_t* Kp    = (ushort_t*)(ws + 13 * MB);  // 8 MB
  ushort_t* Vp    = (ushort_t*)(ws + 21 * MB);  // 8 MB
  ushort_t* Vt    = (ushort_t*)(ws + 29 * MB);  // 8 MB
  ushort_t* Ao    = (ushort_t*)(ws + 37 * MB);  // 4 MB  (total 41 MB)

  // 1) weights: f32 [K][N] -> bf16 [N][K]
  WTP wt; wt.src[0] = Wq; wt.src[1] = Wk; wt.src[2] = Wv; wt.src[3] = Wo;
  wt.dst[0] = WqT; wt.dst[1] = WkT; wt.dst[2] = WvT; wt.dst[3] = WoT;
  wtrans_k<<<dim3(16, 16, 4), 256, 0, stream>>>(wt);

  // 2) mask -> additive f32
  mask_prep<<<1, 256, 0, stream>>>(mask, maskf, B_ * NK_);

  // 3) fused projections (SCALE folded into Qp): 640 blocks
  Proj3P pp;
  pp.A[0] = query; pp.A[1] = key; pp.A[2] = value;
  pp.Bt[0] = WqT;  pp.Bt[1] = WkT; pp.Bt[2] = WvT;
  pp.bias[0] = bq; pp.bias[1] = bk; pp.bias[2] = bv;
  pp.C[0] = Qp;    pp.C[1] = Kp;   pp.C[2] = Vp;
  pp.alpha[0] = 0.125f; pp.alpha[1] = 1.0f; pp.alpha[2] = 1.0f;
  proj3_k<<<dim3(8, 80), 256, 0, stream>>>(pp);

  // 4) V -> Vt [B, D, NK]
  TPtrs vt; vt.src[0] = Vp; vt.src[1] = Vp + (size_t)NK_ * D_;
  vt.dst[0] = Vt; vt.dst[1] = Vt + (size_t)D_ * NK_;
  vtrans_k<<<dim3(16, 32, 2), 256, 0, stream>>>(vt, NK_, D_);

  // 5) fused attention
  flash_attn<<<dim3(NQ_ / 64, H_, B_), 256, 0, stream>>>(Qp, Kp, Vt, abias, maskf, Ao);

  // 6) output projection -> d_out (f32)
  gemm_out_k<<<dim3(8, 16), 256, 0, stream>>>(Ao, WoT, bo, out);
}

// Round 4
// 552.979 us; speedup vs baseline: 1.0705x; 1.0299x over previous
//
#include <hip/hip_runtime.h>
#include <stdint.h>
#include <math.h>

typedef unsigned short ushort_t;                                 // bf16 bits
typedef short bf16x8 __attribute__((ext_vector_type(8)));        // 8 bf16 = 4 VGPRs
typedef float f32x4  __attribute__((ext_vector_type(4)));

#define B_   2
#define NQ_  1024
#define NK_  2048
#define D_   1024
#define H_   16
#define HD_  64

__device__ __forceinline__ ushort_t f2b(float f) {               // RNE (cold paths)
  union { float f; unsigned int i; } x; x.f = f;
  unsigned int r = (x.i + 0x7FFFu + ((x.i >> 16) & 1u)) >> 16;
  return (ushort_t)r;
}
__device__ __forceinline__ ushort_t f2b_fast(float f) {          // round-nearest-away
  union { float f; unsigned int i; } x; x.f = f;
  return (ushort_t)((x.i + 0x8000u) >> 16);
}
// async global->LDS, 16B per lane, LDS dest = wave-uniform base + lane*16
__device__ __forceinline__ void g2l16(const void* g, void* l) {
  __builtin_amdgcn_global_load_lds(
      (const __attribute__((address_space(1))) unsigned int*)g,
      (__attribute__((address_space(3))) unsigned int*)l, 16, 0, 0);
}
__device__ __forceinline__ f32x4 mfma16(bf16x8 a, bf16x8 b, f32x4 c) {
  return __builtin_amdgcn_mfma_f32_16x16x32_bf16(a, b, c, 0, 0, 0);
}

// ---------------------------------------------------------------------------
// GEMM tile body (m97 structure): C[128,128] = (A[128,K] @ Bt[128,K]^T + bias)*alpha
// A bf16 via global_load_lds. C: bf16 or f32. BK=64, 4 waves (2x2), 4x4 MFMA/wave
// ---------------------------------------------------------------------------
template <bool C_F32>
__device__ __forceinline__ void gemm_tile(
    const ushort_t* __restrict__ A, const ushort_t* __restrict__ Bt,
    const float* __restrict__ bias, void* __restrict__ Cv,
    int m0, int n0, float alpha)
{
  constexpr int N = 1024, K = 1024, BK = 64;
  __shared__ __align__(16) ushort_t As[128 * BK];
  __shared__ __align__(16) ushort_t Bs[128 * BK];
  const int tid  = threadIdx.x;
  const int wid  = tid >> 6, lane = tid & 63;
  const int quad = lane >> 4, l15 = lane & 15;
  const int wm = (wid & 1) * 64,  wn = (wid >> 1) * 64;
  const int srow = tid >> 3, scol = (tid & 7) * 8;  // 32 rows x 8-elem chunks / issue

  const ushort_t* aBase = A  + (size_t)(m0 + srow) * K + scol;
  const ushort_t* bBase = Bt + (size_t)(n0 + srow) * K + scol;
  ushort_t* asDst = As + tid * 8;
  ushort_t* bsDst = Bs + tid * 8;

  f32x4 acc[4][4];
#pragma unroll
  for (int i = 0; i < 4; i++)
#pragma unroll
    for (int j = 0; j < 4; j++) { f32x4 z = {0.f,0.f,0.f,0.f}; acc[i][j] = z; }

  for (int k0 = 0; k0 < K; k0 += BK) {
    __syncthreads();
#pragma unroll
    for (int j = 0; j < 4; j++) {
      g2l16(aBase + (size_t)j * 32 * K + k0, asDst + j * 2048);
      g2l16(bBase + (size_t)j * 32 * K + k0, bsDst + j * 2048);
    }
    asm volatile("s_waitcnt vmcnt(0)" ::: "memory");
    __syncthreads();
#pragma unroll
    for (int ks = 0; ks < 2; ks++) {
      bf16x8 af[4], bfr[4];
#pragma unroll
      for (int t = 0; t < 4; t++) {
        af[t]  = *(const bf16x8*)(As + (wm + t * 16 + l15) * BK + ks * 32 + quad * 8);
        bfr[t] = *(const bf16x8*)(Bs + (wn + t * 16 + l15) * BK + ks * 32 + quad * 8);
      }
#pragma unroll
      for (int mt = 0; mt < 4; mt++)
#pragma unroll
        for (int nt = 0; nt < 4; nt++)
          acc[mt][nt] = mfma16(af[mt], bfr[nt], acc[mt][nt]);
    }
  }
  // epilogue: C/D layout col=lane&15, row=quad*4+reg
  float bn[4];
#pragma unroll
  for (int nt = 0; nt < 4; nt++) bn[nt] = bias[n0 + wn + nt * 16 + l15];
#pragma unroll
  for (int mt = 0; mt < 4; mt++) {
    const int mb = m0 + wm + mt * 16 + quad * 4;
#pragma unroll
    for (int nt = 0; nt < 4; nt++) {
      const int n = n0 + wn + nt * 16 + l15;
#pragma unroll
      for (int r = 0; r < 4; r++) {
        const float val = (acc[mt][nt][r] + bn[nt]) * alpha;
        if constexpr (C_F32) ((float*)Cv)[(size_t)(mb + r) * N + n] = val;
        else ((ushort_t*)Cv)[(size_t)(mb + r) * N + n] = f2b_fast(val);
      }
    }
  }
}

// fused Q/K/V projections: grid (8, 80); y<16 -> Q, y<48 -> K, else V
struct Proj3P {
  const ushort_t* A[3]; const ushort_t* Bt[3]; const float* bias[3];
  ushort_t* C[3]; float alpha[3];
};

__global__ __launch_bounds__(256) void proj3_k(Proj3P p) {
  const int y = blockIdx.y;
  const int i = (y < 16) ? 0 : (y < 48 ? 1 : 2);
  const int my = y - ((i == 0) ? 0 : (i == 1) ? 16 : 48);
  gemm_tile<false>(p.A[i], p.Bt[i], p.bias[i], p.C[i],
                   my * 128, blockIdx.x * 128, p.alpha[i]);
}

__global__ __launch_bounds__(256) void gemm_out_k(
    const ushort_t* __restrict__ A, const ushort_t* __restrict__ Bt,
    const float* __restrict__ bias, float* __restrict__ C) {
  gemm_tile<true>(A, Bt, bias, C, blockIdx.y * 128, blockIdx.x * 128, 1.0f);
}

// ---------------------------------------------------------------------------
// prep: z<4 -> weight transpose+convert; z==4 -> qkv f32->bf16; z==5 -> mask
// ---------------------------------------------------------------------------
struct PrepP {
  const float* W[4]; ushort_t* WT[4];
  const float* qkv[3]; ushort_t* qkvb[3];
  const unsigned char* mraw; float* maskf;
};

__global__ __launch_bounds__(256) void prep_k(PrepP p) {
  const int z = blockIdx.z;
  const int tid = threadIdx.x;
  if (z < 4) {
    constexpr int Kd = 1024, Nd = 1024;
    __shared__ ushort_t t[64][72];
    const float* X = p.W[z];
    ushort_t*    Y = p.WT[z];
    const int rt = blockIdx.y * 64, ct = blockIdx.x * 64;
    const int lr = tid >> 3, lc = (tid & 7) * 8;
#pragma unroll
    for (int j = 0; j < 2; j++) {
      const float* px = X + (size_t)(rt + j * 32 + lr) * Nd + ct + lc;
      float4 x = *(const float4*)px;
      float4 y = *(const float4*)(px + 4);
      ushort_t* tr = &t[j * 32 + lr][lc];
      tr[0] = f2b(x.x); tr[1] = f2b(x.y); tr[2] = f2b(x.z); tr[3] = f2b(x.w);
      tr[4] = f2b(y.x); tr[5] = f2b(y.y); tr[6] = f2b(y.z); tr[7] = f2b(y.w);
    }
    __syncthreads();
#pragma unroll
    for (int j = 0; j < 2; j++) {
      bf16x8 w;
#pragma unroll
      for (int i = 0; i < 8; i++) ((ushort_t*)&w)[i] = t[lc + i][j * 32 + lr];
      *(bf16x8*)(Y + (size_t)(ct + j * 32 + lr) * Kd + rt + lc) = w;
    }
  } else if (z == 4) {
    // convert q|k|v f32 -> bf16, chunks of 8 elements
    const size_t nq = (size_t)B_ * NQ_ * D_;          // 2,097,152
    const size_t nk = (size_t)B_ * NK_ * D_;          // 4,194,304
    const size_t nchunk = (nq + 2 * nk) / 8;          // 1,310,720
    size_t c = (size_t)(blockIdx.y * 16 + blockIdx.x) * 256 + tid;
    for (; c < nchunk; c += 65536) {
      const size_t off = c * 8;
      int t_; size_t rel;
      if (off < nq)            { t_ = 0; rel = off; }
      else if (off < nq + nk)  { t_ = 1; rel = off - nq; }
      else                     { t_ = 2; rel = off - nq - nk; }
      const unsigned* src = (const unsigned*)(p.qkv[t_] + rel);
      uint4 x = *(const uint4*)src;
      uint4 y = *(const uint4*)(src + 4);
      uint4 o;
      o.x = ((x.y + 0x8000u) & 0xFFFF0000u) | ((x.x + 0x8000u) >> 16);
      o.y = ((x.w + 0x8000u) & 0xFFFF0000u) | ((x.z + 0x8000u) >> 16);
      o.z = ((y.y + 0x8000u) & 0xFFFF0000u) | ((y.x + 0x8000u) >> 16);
      o.w = ((y.w + 0x8000u) & 0xFFFF0000u) | ((y.z + 0x8000u) >> 16);
      *(uint4*)(p.qkvb[t_] + rel) = o;
    }
  } else {
    if (blockIdx.x != 0 || blockIdx.y != 0) return;
    // mask prep: sniff uint8 vs int32, emit additive f32 (0 / -1e30)
    __shared__ int is_u8;
    if (tid == 0) is_u8 = 0;
    __syncthreads();
    const int n = B_ * NK_;
    int nz = 0;
    for (int i = tid; i < n; i += 256)
      if ((i & 3) != 0 && p.mraw[i] != 0) nz = 1;
    if (nz) is_u8 = 1;            // benign race, idempotent
    __syncthreads();
    const int u8 = is_u8;
    const int* mi = (const int*)p.mraw;
    for (int k = tid; k < n; k += 256) {
      int v = u8 ? (int)p.mraw[k] : mi[k];
      p.maskf[k] = v ? -1e30f : 0.0f;
    }
  }
}

// ---------------------------------------------------------------------------
// bf16 64x64-tile transpose (Vp [NK][D] -> Vt [D][NK]), batched over z
// ---------------------------------------------------------------------------
struct TPtrs { const ushort_t* src[2]; ushort_t* dst[2]; };

__global__ __launch_bounds__(256) void vtrans_k(TPtrs p, int R, int C) {
  __shared__ ushort_t t[64][68];
  const ushort_t* X = p.src[blockIdx.z];
  ushort_t*       Y = p.dst[blockIdx.z];
  const int rt = blockIdx.y * 64, ct = blockIdx.x * 64;
  const int tid = threadIdx.x;
  const int lr = tid >> 3, lc = (tid & 7) * 8;
#pragma unroll
  for (int j = 0; j < 2; j++) {
    bf16x8 v = *(const bf16x8*)(X + (size_t)(rt + j * 32 + lr) * C + ct + lc);
#pragma unroll
    for (int i = 0; i < 8; i++) t[j * 32 + lr][lc + i] = ((ushort_t*)&v)[i];
  }
  __syncthreads();
#pragma unroll
  for (int j = 0; j < 2; j++) {
    bf16x8 w;
#pragma unroll
    for (int i = 0; i < 8; i++) ((ushort_t*)&w)[i] = t[lc + i][j * 32 + lr];
    *(bf16x8*)(Y + (size_t)(ct + j * 32 + lr) * R + rt + lc) = w;
  }
}

// ---------------------------------------------------------------------------
// flash attention, split-K over 2 key-halves:
// grid (NQ/64, H, B*2), 256 threads = 4 waves x 16 q-rows, 16 k-iters/block.
// Outputs unnormalized O (f32) + per-row (m, l) for the combine pass.
// ---------------------------------------------------------------------------
__global__ __launch_bounds__(256) void flash_split(
    const ushort_t* __restrict__ Qp, const ushort_t* __restrict__ Kp,
    const ushort_t* __restrict__ Vt, const float* __restrict__ bias,
    const float* __restrict__ maskf, float* __restrict__ Opart,
    float2* __restrict__ ml)
{
  __shared__ __align__(16) ushort_t Ks[64 * 64];     // [key][hd]      8 KB
  __shared__ __align__(16) ushort_t Vs[64 * 64];     // [hd][key]      8 KB
  __shared__ __align__(16) ushort_t Ps[4][16 * 64];  // per-wave P     8 KB
  __shared__ __align__(16) float    Bf[64 * 64];     // bias tile     16 KB
  const int zz = blockIdx.z;                 // b*2 + half
  const int b = zz >> 1, half = zz & 1;
  const int h = blockIdx.y, q0 = blockIdx.x * 64;
  const int k_beg = half * (NK_ / 2), k_end = k_beg + NK_ / 2;
  const int tid  = threadIdx.x, wid = tid >> 6, lane = tid & 63;
  const int quad = lane >> 4, l15 = lane & 15;
  const int qw   = q0 + wid * 16;
  const int srow = tid >> 3, scol = (tid & 7) * 8;

  // Q A-fragments: m = l15 (q-row), k = quad*8+j (hd)
  bf16x8 qf[2];
#pragma unroll
  for (int ks = 0; ks < 2; ks++)
    qf[ks] = *(const bf16x8*)(Qp + (size_t)(b * NQ_ + qw + l15) * D_ + h * HD_ + ks * 32 + quad * 8);

  f32x4 o[4];
#pragma unroll
  for (int nt = 0; nt < 4; nt++) { f32x4 z = {0.f,0.f,0.f,0.f}; o[nt] = z; }
  float mrow[4] = {-INFINITY, -INFINITY, -INFINITY, -INFINITY};
  float lrow[4] = {0.f, 0.f, 0.f, 0.f};

  const float*    biasBase = bias + ((size_t)(b * H_ + h) * NQ_ + q0) * NK_;
  const float*    mBase    = maskf + b * NK_;
  const ushort_t* kBase    = Kp + (size_t)(b * NK_ + srow) * D_ + h * HD_ + scol;
  const ushort_t* vBase    = Vt + (size_t)(b * D_ + h * HD_ + srow) * NK_ + scol;
  const int bRow0 = wid * 16 + (lane >> 4);
  const int bCol  = l15 * 4;

  for (int k0 = k_beg; k0 < k_end; k0 += 64) {
    __syncthreads();
#pragma unroll
    for (int j = 0; j < 2; j++) {
      g2l16(kBase + (size_t)(k0 + j * 32) * D_, Ks + tid * 8 + j * 2048);
      g2l16(vBase + (size_t)j * 32 * NK_ + k0, Vs + tid * 8 + j * 2048);
    }
#pragma unroll
    for (int j = 0; j < 4; j++)
      g2l16(biasBase + (size_t)(bRow0 + j * 4) * NK_ + k0 + bCol,
            (char*)Bf + (wid * 16 + j * 4) * 256);
    asm volatile("s_waitcnt vmcnt(0)" ::: "memory");
    __syncthreads();

    // S = Q K^T (Qp pre-scaled)
    f32x4 s[4];
#pragma unroll
    for (int nt = 0; nt < 4; nt++) { f32x4 z = {0.f,0.f,0.f,0.f}; s[nt] = z; }
#pragma unroll
    for (int ks = 0; ks < 2; ks++)
#pragma unroll
      for (int nt = 0; nt < 4; nt++) {
        bf16x8 kf = *(const bf16x8*)(Ks + (nt * 16 + l15) * 64 + ks * 32 + quad * 8);
        s[nt] = mfma16(qf[ks], kf, s[nt]);
      }

    // logits (row = quad*4+r, key = k0 + nt*16 + l15)
    float z[4][4];
#pragma unroll
    for (int nt = 0; nt < 4; nt++) {
      const float mk = mBase[k0 + nt * 16 + l15];
#pragma unroll
      for (int r = 0; r < 4; r++)
        z[nt][r] = s[nt][r] + Bf[(wid * 16 + quad * 4 + r) * 64 + nt * 16 + l15] + mk;
    }

    // online softmax
    float alpha_[4];
#pragma unroll
    for (int r = 0; r < 4; r++) {
      float v = fmaxf(fmaxf(z[0][r], z[1][r]), fmaxf(z[2][r], z[3][r]));
      v = fmaxf(v, __shfl_xor(v, 1)); v = fmaxf(v, __shfl_xor(v, 2));
      v = fmaxf(v, __shfl_xor(v, 4)); v = fmaxf(v, __shfl_xor(v, 8));
      float mn = fmaxf(mrow[r], v);
      alpha_[r] = __expf(mrow[r] - mn);
      mrow[r] = mn;
    }
    float rsum[4] = {0.f, 0.f, 0.f, 0.f};
#pragma unroll
    for (int nt = 0; nt < 4; nt++)
#pragma unroll
      for (int r = 0; r < 4; r++) {
        float p = __expf(z[nt][r] - mrow[r]);
        rsum[r] += p;
        Ps[wid][(quad * 4 + r) * 64 + nt * 16 + l15] = f2b_fast(p);
      }
#pragma unroll
    for (int r = 0; r < 4; r++) {
      float v = rsum[r];
      v += __shfl_xor(v, 1); v += __shfl_xor(v, 2);
      v += __shfl_xor(v, 4); v += __shfl_xor(v, 8);
      lrow[r] = lrow[r] * alpha_[r] + v;
    }
#pragma unroll
    for (int nt = 0; nt < 4; nt++) {
      f32x4 t = o[nt];
#pragma unroll
      for (int r = 0; r < 4; r++) t[r] *= alpha_[r];
      o[nt] = t;
    }
    // O += P @ V (same-wave LDS write->read, in-order pipe, no barrier needed)
#pragma unroll
    for (int ks = 0; ks < 2; ks++) {
      bf16x8 pa = *(const bf16x8*)(&Ps[wid][l15 * 64 + ks * 32 + quad * 8]);
#pragma unroll
      for (int nt = 0; nt < 4; nt++) {
        bf16x8 vf = *(const bf16x8*)(Vs + (nt * 16 + l15) * 64 + ks * 32 + quad * 8);
        o[nt] = mfma16(pa, vf, o[nt]);
      }
    }
  }
  // store unnormalized partials: Opart[(zz*H+h)*NQ + q][hd], ml[(zz*H+h)*NQ + q]
  const size_t rowBase = ((size_t)zz * H_ + h) * NQ_ + qw + quad * 4;
#pragma unroll
  for (int nt = 0; nt < 4; nt++)
#pragma unroll
    for (int r = 0; r < 4; r++)
      Opart[(rowBase + r) * HD_ + nt * 16 + l15] = o[nt][r];
  if (l15 == 0) {
#pragma unroll
    for (int r = 0; r < 4; r++) {
      float2 v; v.x = mrow[r]; v.y = lrow[r];
      ml[rowBase + r] = v;
    }
  }
}

// combine: O = (w1*O1 + w2*O2) / (w1*l1 + w2*l2), write bf16 Ao [B,NQ,D]
__global__ __launch_bounds__(256) void combine_k(
    const float* __restrict__ Opart, const float2* __restrict__ ml,
    ushort_t* __restrict__ Ao)
{
  const int tid = threadIdx.x;
  const int row = blockIdx.x * 4 + (tid >> 6);   // 0 .. B*H*NQ-1
  const int hd  = tid & 63;
  const int bh = row >> 10, q = row & (NQ_ - 1);
  const int b = bh >> 4, h = bh & (H_ - 1);
  const size_t i1 = ((size_t)(b * 2 + 0) * H_ + h) * NQ_ + q;
  const size_t i2 = ((size_t)(b * 2 + 1) * H_ + h) * NQ_ + q;
  const float2 a = ml[i1], c = ml[i2];
  const float M  = fmaxf(a.x, c.x);
  const float w1 = __expf(a.x - M), w2 = __expf(c.x - M);
  const float l  = w1 * a.y + w2 * c.y;
  const float o  = (w1 * Opart[i1 * HD_ + hd] + w2 * Opart[i2 * HD_ + hd]) / l;
  Ao[((size_t)(b * NQ_ + q)) * D_ + h * HD_ + hd] = f2b_fast(o);
}

// ---------------------------------------------------------------------------
extern "C" void kernel_launch(void* const* d_in, const int* in_sizes, int n_in,
                              void* d_out, int out_size, void* d_ws, size_t ws_size,
                              hipStream_t stream)
{
  const float* query = (const float*)d_in[0];
  const float* key   = (const float*)d_in[1];
  const float* value = (const float*)d_in[2];
  const float* abias = (const float*)d_in[3];
  const unsigned char* mask = (const unsigned char*)d_in[4];
  const float* Wq = (const float*)d_in[5];
  const float* bq = (const float*)d_in[6];
  const float* Wk = (const float*)d_in[7];
  const float* bk = (const float*)d_in[8];
  const float* Wv = (const float*)d_in[9];
  const float* bv = (const float*)d_in[10];
  const float* Wo = (const float*)d_in[11];
  const float* bo = (const float*)d_in[12];
  float* out = (float*)d_out;

  char* ws = (char*)d_ws;
  const size_t MB = 1ull << 20;
  ushort_t* WqT   = (ushort_t*)(ws + 0 * MB);   // 2 MB
  ushort_t* WkT   = (ushort_t*)(ws + 2 * MB);   // 2 MB
  ushort_t* WvT   = (ushort_t*)(ws + 4 * MB);   // 2 MB
  ushort_t* WoT   = (ushort_t*)(ws + 6 * MB);   // 2 MB
  float*    maskf = (float*)   (ws + 8 * MB);   // 16 KB (1 MB reserved)
  ushort_t* Qb    = (ushort_t*)(ws + 9 * MB);   // 4 MB  bf16 query
  ushort_t* Kb    = (ushort_t*)(ws + 13 * MB);  // 8 MB  bf16 key
  ushort_t* Vb    = (ushort_t*)(ws + 21 * MB);  // 8 MB  bf16 value
  ushort_t* Qp    = (ushort_t*)(ws + 29 * MB);  // 4 MB
  ushort_t* Kp    = (ushort_t*)(ws + 33 * MB);  // 8 MB
  ushort_t* Vp    = (ushort_t*)(ws + 41 * MB);  // 8 MB
  ushort_t* Vt    = (ushort_t*)(ws + 49 * MB);  // 8 MB
  ushort_t* Ao    = (ushort_t*)(ws + 57 * MB);  // 4 MB
  float*    Opart = (float*)   (ws + 61 * MB);  // 16 MB
  float2*   mlbuf = (float2*)  (ws + 77 * MB);  // 256 KB   (total 78 MB)

  // 1) prep: weights f32[K][N] -> bf16[N][K]; qkv f32 -> bf16; mask -> f32
  PrepP pr;
  pr.W[0] = Wq; pr.W[1] = Wk; pr.W[2] = Wv; pr.W[3] = Wo;
  pr.WT[0] = WqT; pr.WT[1] = WkT; pr.WT[2] = WvT; pr.WT[3] = WoT;
  pr.qkv[0] = query; pr.qkv[1] = key; pr.qkv[2] = value;
  pr.qkvb[0] = Qb; pr.qkvb[1] = Kb; pr.qkvb[2] = Vb;
  pr.mraw = mask; pr.maskf = maskf;
  prep_k<<<dim3(16, 16, 6), 256, 0, stream>>>(pr);

  // 2) fused projections (SCALE folded into Qp): 640 blocks, pure bf16 m97 path
  Proj3P pp;
  pp.A[0] = Qb;    pp.A[1] = Kb;   pp.A[2] = Vb;
  pp.Bt[0] = WqT;  pp.Bt[1] = WkT; pp.Bt[2] = WvT;
  pp.bias[0] = bq; pp.bias[1] = bk; pp.bias[2] = bv;
  pp.C[0] = Qp;    pp.C[1] = Kp;   pp.C[2] = Vp;
  pp.alpha[0] = 0.125f; pp.alpha[1] = 1.0f; pp.alpha[2] = 1.0f;
  proj3_k<<<dim3(8, 80), 256, 0, stream>>>(pp);

  // 3) V -> Vt [B, D, NK]
  TPtrs vt; vt.src[0] = Vp; vt.src[1] = Vp + (size_t)NK_ * D_;
  vt.dst[0] = Vt; vt.dst[1] = Vt + (size_t)D_ * NK_;
  vtrans_k<<<dim3(16, 32, 2), 256, 0, stream>>>(vt, NK_, D_);

  // 4) flash attention, split over 2 key-halves: 1024 blocks (4/CU)
  flash_split<<<dim3(NQ_ / 64, H_, B_ * 2), 256, 0, stream>>>(
      Qp, Kp, Vt, abias, maskf, Opart, mlbuf);

  // 5) combine halves -> Ao bf16
  combine_k<<<dim3(B_ * H_ * NQ_ / 4), 256, 0, stream>>>(Opart, mlbuf, Ao);

  // 6) output projection -> d_out (f32)
  gemm_out_k<<<dim3(8, 16), 256, 0, stream>>>(Ao, WoT, bo, out);
}